// Round 2
// baseline (1408.514 us; speedup 1.0000x reference)
//
#include <hip/hip_runtime.h>
#include <stdint.h>

typedef unsigned short u16;
typedef __attribute__((ext_vector_type(8))) short short8;
typedef __attribute__((ext_vector_type(4))) float f32x4;

#define MED3(a, b, c) __builtin_amdgcn_fmed3f((a), (b), (c))

static constexpr int Bn = 128, NWAY = 50, Cn = 64, Pn = 441, Mn = 2205;
static constexpr int PPAD = 448;   // 441 padded to 7*64
static constexpr int MPAD = 2240;  // 2205 padded to 35*64
static constexpr int MT = 64;      // m per LDS tile
static constexpr int NTILE = MPAD / MT;  // 35
static constexpr float NEG = -3.0e38f;

__device__ __forceinline__ u16 f2bf(float f) {
  union { float f; uint32_t u; } x; x.f = f;
  return (u16)((x.u + 0x7FFFu + ((x.u >> 16) & 1u)) >> 16);  // RNE
}

// qn[b][p][c] bf16, p padded to 448 with zeros. Norm over c per (b,p).
__global__ void qnorm_kernel(const float* __restrict__ q, u16* __restrict__ qn) {
  int idx = blockIdx.x * 256 + threadIdx.x;
  if (idx >= Bn * PPAD) return;
  int b = idx / PPAD, p = idx - b * PPAD;
  u16* dst = qn + (size_t)idx * Cn;
  if (p >= Pn) {
    uint4 z = {0u, 0u, 0u, 0u};
#pragma unroll
    for (int c = 0; c < Cn; c += 8) *(uint4*)(dst + c) = z;
    return;
  }
  const float* src = q + (size_t)b * Cn * Pn + p;
  float v[Cn];
  float ss = 0.f;
#pragma unroll
  for (int c = 0; c < Cn; ++c) {
    float x = src[(size_t)c * Pn];  // coalesced over lanes (consecutive p)
    v[c] = x;
    ss += x * x;
  }
  float inv = 1.0f / sqrtf(ss);
#pragma unroll
  for (int c = 0; c < Cn; c += 8) {
    uint4 w;
    w.x = (uint32_t)f2bf(v[c + 0] * inv) | ((uint32_t)f2bf(v[c + 1] * inv) << 16);
    w.y = (uint32_t)f2bf(v[c + 2] * inv) | ((uint32_t)f2bf(v[c + 3] * inv) << 16);
    w.z = (uint32_t)f2bf(v[c + 4] * inv) | ((uint32_t)f2bf(v[c + 5] * inv) << 16);
    w.w = (uint32_t)f2bf(v[c + 6] * inv) | ((uint32_t)f2bf(v[c + 7] * inv) << 16);
    *(uint4*)(dst + c) = w;
  }
}

// sn[j][m][c] bf16 (transposed from S[j][c][m]), m padded to 2240 with zeros.
__global__ void snorm_kernel(const float* __restrict__ S, u16* __restrict__ sn) {
  int idx = blockIdx.x * 256 + threadIdx.x;
  if (idx >= NWAY * MPAD) return;
  int j = idx / MPAD, m = idx - j * MPAD;
  u16* dst = sn + (size_t)idx * Cn;
  if (m >= Mn) {
    uint4 z = {0u, 0u, 0u, 0u};
#pragma unroll
    for (int c = 0; c < Cn; c += 8) *(uint4*)(dst + c) = z;
    return;
  }
  const float* src = S + (size_t)j * Cn * Mn + m;
  float v[Cn];
  float ss = 0.f;
#pragma unroll
  for (int c = 0; c < Cn; ++c) {
    float x = src[(size_t)c * Mn];  // coalesced over lanes (consecutive m)
    v[c] = x;
    ss += x * x;
  }
  float inv = 1.0f / sqrtf(ss);
#pragma unroll
  for (int c = 0; c < Cn; c += 8) {
    uint4 w;
    w.x = (uint32_t)f2bf(v[c + 0] * inv) | ((uint32_t)f2bf(v[c + 1] * inv) << 16);
    w.y = (uint32_t)f2bf(v[c + 2] * inv) | ((uint32_t)f2bf(v[c + 3] * inv) << 16);
    w.z = (uint32_t)f2bf(v[c + 4] * inv) | ((uint32_t)f2bf(v[c + 5] * inv) << 16);
    w.w = (uint32_t)f2bf(v[c + 6] * inv) | ((uint32_t)f2bf(v[c + 7] * inv) << 16);
    *(uint4*)(dst + c) = w;
  }
}

// Stage one 64x64 bf16 tile (8KB, 512 16B-chunks) of sn[j] into LDS buf.
// 448 threads stage chunk tid; wave 0 additionally stages chunks 448..511.
// Linear LDS dest (global_load_lds requirement), inverse-swizzled GLOBAL
// source so the swizzled ds_read below is bank-conflict-free (rule #21).
#define STAGE(BUF, T)                                                          \
  do {                                                                         \
    const u16* _tile = Sj + (size_t)(T) * (MT * Cn);                           \
    __builtin_amdgcn_global_load_lds(                                          \
        (const __attribute__((address_space(1))) void*)(_tile + soff0),        \
        (__attribute__((address_space(3))) void*)(&sb[(BUF)][loff0]), 16, 0, 0);\
    if (tid < 64) {                                                            \
      __builtin_amdgcn_global_load_lds(                                        \
          (const __attribute__((address_space(1))) void*)(_tile + soff1),      \
          (__attribute__((address_space(3))) void*)(&sb[(BUF)][loff1]), 16, 0, \
          0);                                                                  \
    }                                                                          \
  } while (0)

// Compute one 64-m tile: 4 m-frags x 4 p-frags x 2 k-steps of
// mfma_f32_16x16x32_bf16, fused med3 top-3 update (3 VALU ops/element).
// C of the first MFMA is a loop-invariant zero vector (no per-dot v_movs).
#define COMPUTE_TILE(BASE0, BASE1, TAIL, TBASE)                                \
  do {                                                                         \
    _Pragma("unroll")                                                          \
    for (int mf = 0; mf < 4; ++mf) {                                           \
      short8 bf0 = *(const short8*)((BASE0) + mf * 16 * Cn);                   \
      short8 bf1 = *(const short8*)((BASE1) + mf * 16 * Cn);                   \
      _Pragma("unroll")                                                        \
      for (int pf = 0; pf < 4; ++pf) {                                         \
        f32x4 acc =                                                            \
            __builtin_amdgcn_mfma_f32_16x16x32_bf16(afrag[pf][0], bf0, z4, 0,  \
                                                    0, 0);                     \
        acc = __builtin_amdgcn_mfma_f32_16x16x32_bf16(afrag[pf][1], bf1, acc,  \
                                                      0, 0, 0);                \
        _Pragma("unroll")                                                      \
        for (int rr = 0; rr < 4; ++rr) {                                       \
          float v = acc[rr];                                                   \
          if (TAIL) {                                                          \
            if ((TBASE) + mf * 16 + lr >= Mn) v = NEG;                         \
          }                                                                    \
          const int e = pf * 4 + rr;                                           \
          float o2 = MED3(t1[e], t2[e], v);                                    \
          float o1 = MED3(t0[e], t1[e], v);                                    \
          t0[e] = fmaxf(t0[e], v);                                             \
          t1[e] = o1;                                                          \
          t2[e] = o2;                                                          \
        }                                                                      \
      }                                                                        \
    }                                                                          \
  } while (0)

__global__ __launch_bounds__(448, 1) void knn_topk_kernel(
    const u16* __restrict__ qn, const u16* __restrict__ sn,
    float* __restrict__ out) {
  __shared__ __align__(16) u16 sb[2][MT * Cn];  // 2 x 8KB double buffer
  __shared__ float wsum[7];

  const int bid = blockIdx.x;
  const int b = bid / NWAY;
  const int j = bid - b * NWAY;
  const int tid = threadIdx.x;
  const int wave = tid >> 6;
  const int lane = tid & 63;
  const int lr = lane & 15;
  const int lg = lane >> 4;

  const u16* Qb = qn + (size_t)b * PPAD * Cn;
  const u16* Sj = sn + (size_t)j * MPAD * Cn;

  // staging: 512 16B-chunks; chunk q -> LDS row q>>3, seg q&7;
  // global source seg is XOR-swizzled by row&7 (involution).
  const int q0 = tid, q1 = tid + 448;
  const int soff0 = ((q0 >> 3) * Cn) + ((((q0 & 7) ^ ((q0 >> 3) & 7))) * 8);
  const int soff1 = ((q1 >> 3) * Cn) + ((((q1 & 7) ^ ((q1 >> 3) & 7))) * 8);
  const int loff0 = q0 * 8, loff1 = q1 * 8;

  // swizzled read offsets (elements within a 64-elem LDS row): seg=ks*4+lg
  const int rs0 = ((0 + lg) ^ (lr & 7)) * 8;
  const int rs1 = ((4 + lg) ^ (lr & 7)) * 8;
  // static ds_read bases per buffer/k-step; mf adds a compile-time offset
  const u16* rb0k0 = sb[0] + lr * Cn + rs0;
  const u16* rb0k1 = sb[0] + lr * Cn + rs1;
  const u16* rb1k0 = sb[1] + lr * Cn + rs0;
  const u16* rb1k1 = sb[1] + lr * Cn + rs1;

  const f32x4 z4 = {0.f, 0.f, 0.f, 0.f};  // persistent zero C-operand

  // A fragments: this wave's 64 p-rows; 4 p-frags x 2 k-steps
  const int p_base = wave * 64;
  short8 afrag[4][2];
#pragma unroll
  for (int pf = 0; pf < 4; ++pf) {
    const u16* ap = Qb + (size_t)(p_base + pf * 16 + lr) * Cn + lg * 8;
    afrag[pf][0] = *(const short8*)(ap);
    afrag[pf][1] = *(const short8*)(ap + 32);
  }

  // running top-3 per (p-frag, acc-reg) entry; cols == lr (mod 16)
  float t0[16], t1[16], t2[16];
#pragma unroll
  for (int e = 0; e < 16; ++e) { t0[e] = NEG; t1[e] = NEG; t2[e] = NEG; }

  STAGE(0, 0);
  __syncthreads();  // vmcnt(0) drain + barrier

  // 34 full tiles, unrolled x2 so buffer selection is static
  for (int t = 0; t < NTILE - 1; t += 2) {
    STAGE(1, t + 1);
    COMPUTE_TILE(rb0k0, rb0k1, 0, 0);
    __syncthreads();
    STAGE(0, t + 2);
    COMPUTE_TILE(rb1k0, rb1k1, 0, 0);
    __syncthreads();
  }
  // tail tile 34 (buf 0): mask pad m columns
  COMPUTE_TILE(rb0k0, rb0k1, 1, (NTILE - 1) * MT);

  // finalize: butterfly-merge top-3 across the 16 col-classes of each row
  float total = 0.f;  // nonzero only on lanes with lr==0
#pragma unroll
  for (int pf = 0; pf < 4; ++pf) {
#pragma unroll
    for (int rr = 0; rr < 4; ++rr) {
      const int e = pf * 4 + rr;
      float a0 = t0[e], a1 = t1[e], a2 = t2[e];
#pragma unroll
      for (int sh = 1; sh <= 8; sh <<= 1) {
        float b0 = __shfl_xor(a0, sh, 64);
        float b1 = __shfl_xor(a1, sh, 64);
        float b2 = __shfl_xor(a2, sh, 64);
        float n2 = MED3(a1, a2, b0);
        float n1 = MED3(a0, a1, b0);
        float n0 = fmaxf(a0, b0);
        n2 = MED3(n1, n2, b1);  // b1 <= b0 <= n0: max unneeded
        n1 = MED3(n0, n1, b1);
        n2 = MED3(n1, n2, b2);  // b2 can only land in slot 2
        a0 = n0; a1 = n1; a2 = n2;
      }
      const int prow = p_base + pf * 16 + lg * 4 + rr;
      if (lr == 0 && prow < Pn) total += a0 + a1 + a2;
    }
  }

  // reduce lanes 0,16,32,48 -> lane 0, then across 7 waves
  total += __shfl_xor(total, 16, 64);
  total += __shfl_xor(total, 32, 64);
  if (lane == 0) wsum[wave] = total;
  __syncthreads();
  if (tid == 0) {
    float s = wsum[0];
#pragma unroll
    for (int w = 1; w < 7; ++w) s += wsum[w];
    out[(size_t)b * NWAY + j] = s;
  }
}

extern "C" void kernel_launch(void* const* d_in, const int* in_sizes, int n_in,
                              void* d_out, int out_size, void* d_ws,
                              size_t ws_size, hipStream_t stream) {
  (void)in_sizes; (void)n_in; (void)out_size; (void)ws_size;
  const float* q = (const float*)d_in[0];
  const float* S = (const float*)d_in[1];
  // d_in[2] = av_num == 1 per setup_inputs: geometric-mean branch not taken.
  float* out = (float*)d_out;

  u16* qn = (u16*)d_ws;                               // 128*448*64*2 = 7.34 MB
  u16* sn = qn + (size_t)Bn * PPAD * Cn;              // 50*2240*64*2 = 14.3 MB

  qnorm_kernel<<<(Bn * PPAD) / 256, 256, 0, stream>>>(q, qn);
  snorm_kernel<<<(NWAY * MPAD + 255) / 256, 256, 0, stream>>>(S, sn);
  knn_topk_kernel<<<Bn * NWAY, 448, 0, stream>>>(qn, sn, out);
}

// Round 3
// 950.744 us; speedup vs baseline: 1.4815x; 1.4815x over previous
//
#include <hip/hip_runtime.h>
#include <stdint.h>

typedef unsigned short u16;
typedef __attribute__((ext_vector_type(8))) short short8;
typedef __attribute__((ext_vector_type(4))) float f32x4;

#define MED3(a, b, c) __builtin_amdgcn_fmed3f((a), (b), (c))

static constexpr int Bn = 128, NWAY = 50, Cn = 64, Pn = 441, Mn = 2205;
static constexpr int PPAD = 448;   // 441 padded to 7*64 (= 4 waves * 7 pf * 16)
static constexpr int MPAD = 2240;  // 2205 padded to 35*64
static constexpr int MT = 64;      // m per LDS tile
static constexpr int NTILE = MPAD / MT;  // 35
static constexpr int NPF = 7;      // p-frags per wave (16 p each)
static constexpr float NEG = -3.0e38f;

__device__ __forceinline__ u16 f2bf(float f) {
  union { float f; uint32_t u; } x; x.f = f;
  return (u16)((x.u + 0x7FFFu + ((x.u >> 16) & 1u)) >> 16);  // RNE
}

// qn[b][p][c] bf16, p padded to 448 with zeros. Norm over c per (b,p).
__global__ void qnorm_kernel(const float* __restrict__ q, u16* __restrict__ qn) {
  int idx = blockIdx.x * 256 + threadIdx.x;
  if (idx >= Bn * PPAD) return;
  int b = idx / PPAD, p = idx - b * PPAD;
  u16* dst = qn + (size_t)idx * Cn;
  if (p >= Pn) {
    uint4 z = {0u, 0u, 0u, 0u};
#pragma unroll
    for (int c = 0; c < Cn; c += 8) *(uint4*)(dst + c) = z;
    return;
  }
  const float* src = q + (size_t)b * Cn * Pn + p;
  float v[Cn];
  float ss = 0.f;
#pragma unroll
  for (int c = 0; c < Cn; ++c) {
    float x = src[(size_t)c * Pn];  // coalesced over lanes (consecutive p)
    v[c] = x;
    ss += x * x;
  }
  float inv = 1.0f / sqrtf(ss);
#pragma unroll
  for (int c = 0; c < Cn; c += 8) {
    uint4 w;
    w.x = (uint32_t)f2bf(v[c + 0] * inv) | ((uint32_t)f2bf(v[c + 1] * inv) << 16);
    w.y = (uint32_t)f2bf(v[c + 2] * inv) | ((uint32_t)f2bf(v[c + 3] * inv) << 16);
    w.z = (uint32_t)f2bf(v[c + 4] * inv) | ((uint32_t)f2bf(v[c + 5] * inv) << 16);
    w.w = (uint32_t)f2bf(v[c + 6] * inv) | ((uint32_t)f2bf(v[c + 7] * inv) << 16);
    *(uint4*)(dst + c) = w;
  }
}

// sn[j][m][c] bf16 (transposed from S[j][c][m]), m padded to 2240 with zeros.
__global__ void snorm_kernel(const float* __restrict__ S, u16* __restrict__ sn) {
  int idx = blockIdx.x * 256 + threadIdx.x;
  if (idx >= NWAY * MPAD) return;
  int j = idx / MPAD, m = idx - j * MPAD;
  u16* dst = sn + (size_t)idx * Cn;
  if (m >= Mn) {
    uint4 z = {0u, 0u, 0u, 0u};
#pragma unroll
    for (int c = 0; c < Cn; c += 8) *(uint4*)(dst + c) = z;
    return;
  }
  const float* src = S + (size_t)j * Cn * Mn + m;
  float v[Cn];
  float ss = 0.f;
#pragma unroll
  for (int c = 0; c < Cn; ++c) {
    float x = src[(size_t)c * Mn];  // coalesced over lanes (consecutive m)
    v[c] = x;
    ss += x * x;
  }
  float inv = 1.0f / sqrtf(ss);
#pragma unroll
  for (int c = 0; c < Cn; c += 8) {
    uint4 w;
    w.x = (uint32_t)f2bf(v[c + 0] * inv) | ((uint32_t)f2bf(v[c + 1] * inv) << 16);
    w.y = (uint32_t)f2bf(v[c + 2] * inv) | ((uint32_t)f2bf(v[c + 3] * inv) << 16);
    w.z = (uint32_t)f2bf(v[c + 4] * inv) | ((uint32_t)f2bf(v[c + 5] * inv) << 16);
    w.w = (uint32_t)f2bf(v[c + 6] * inv) | ((uint32_t)f2bf(v[c + 7] * inv) << 16);
    *(uint4*)(dst + c) = w;
  }
}

// Stage one 64x64 bf16 tile (8KB, 512 16B-chunks, 2 per thread) of sn[j] into
// LDS buf. Linear LDS dest (global_load_lds requirement), inverse-swizzled
// GLOBAL source so the swizzled ds_read below is bank-conflict-free (#21).
#define STAGE(BUF, T)                                                          \
  do {                                                                         \
    const u16* _tile = Sj + (size_t)(T) * (MT * Cn);                           \
    __builtin_amdgcn_global_load_lds(                                          \
        (const __attribute__((address_space(1))) void*)(_tile + soff0),        \
        (__attribute__((address_space(3))) void*)(&sb[(BUF)][loff0]), 16, 0, 0);\
    __builtin_amdgcn_global_load_lds(                                          \
        (const __attribute__((address_space(1))) void*)(_tile + soff1),        \
        (__attribute__((address_space(3))) void*)(&sb[(BUF)][loff1]), 16, 0, 0);\
  } while (0)

// Compute one 64-m tile. SWAPPED operands: A = sn tile rows (m), B = qn
// (cols = p). C quad (rr) = 4 m-rows of ONE p (= lane&15) -> t-state is 3
// floats per pf. 4 mf x 7 pf x 2 k-steps; first MFMA uses constant-zero C.
#define COMPUTE_TILE(BASE0, BASE1, TAIL, TBASE)                                \
  do {                                                                         \
    _Pragma("unroll")                                                          \
    for (int mf = 0; mf < 4; ++mf) {                                           \
      short8 av0 = *(const short8*)((BASE0) + mf * 16 * Cn);                   \
      short8 av1 = *(const short8*)((BASE1) + mf * 16 * Cn);                   \
      _Pragma("unroll")                                                        \
      for (int pf = 0; pf < NPF; ++pf) {                                       \
        f32x4 acc =                                                            \
            __builtin_amdgcn_mfma_f32_16x16x32_bf16(av0, bq[pf][0], z4, 0, 0,  \
                                                    0);                        \
        acc = __builtin_amdgcn_mfma_f32_16x16x32_bf16(av1, bq[pf][1], acc, 0,  \
                                                      0, 0);                   \
        _Pragma("unroll")                                                      \
        for (int rr = 0; rr < 4; ++rr) {                                       \
          float v = acc[rr];                                                   \
          if (TAIL) {                                                          \
            if ((TBASE) + mf * 16 + lg4 + rr >= Mn) v = NEG;                   \
          }                                                                    \
          float o2 = MED3(t1[pf], t2[pf], v);                                  \
          float o1 = MED3(t0[pf], t1[pf], v);                                  \
          t0[pf] = fmaxf(t0[pf], v);                                           \
          t1[pf] = o1;                                                         \
          t2[pf] = o2;                                                         \
        }                                                                      \
      }                                                                        \
    }                                                                          \
  } while (0)

__global__ __launch_bounds__(256, 3) void knn_topk_kernel(
    const u16* __restrict__ qn, const u16* __restrict__ sn,
    float* __restrict__ out) {
  __shared__ __align__(16) u16 sb[2][MT * Cn];  // 2 x 8KB double buffer
  __shared__ float wsum[4];

  const int bid = blockIdx.x;
  const int b = bid / NWAY;
  const int j = bid - b * NWAY;
  const int tid = threadIdx.x;
  const int wave = tid >> 6;
  const int lane = tid & 63;
  const int lr = lane & 15;
  const int lg = lane >> 4;
  const int lg4 = lg * 4;

  const u16* Qb = qn + (size_t)b * PPAD * Cn;
  const u16* Sj = sn + (size_t)j * MPAD * Cn;

  // staging: 512 16B-chunks, 2/thread; chunk q -> LDS row q>>3, seg q&7;
  // global source seg is XOR-swizzled by row&7 (involution).
  const int q0 = tid, q1 = tid + 256;
  const int soff0 = ((q0 >> 3) * Cn) + ((((q0 & 7) ^ ((q0 >> 3) & 7))) * 8);
  const int soff1 = ((q1 >> 3) * Cn) + ((((q1 & 7) ^ ((q1 >> 3) & 7))) * 8);
  const int loff0 = q0 * 8, loff1 = q1 * 8;

  // swizzled ds_read offsets: A-frag row = mf*16+lr, seg = ks*4+lg (^ row&7)
  const int rs0 = ((0 + lg) ^ lr /* lr&7 == lr&7; lr<16, (lr&7) */ ) * 8;
  const int rs1 = ((4 + lg) ^ (lr & 7)) * 8;
  // NOTE: rs0 must use (lr & 7) too:
  const int rs0f = ((0 + lg) ^ (lr & 7)) * 8;
  const u16* rb0k0 = sb[0] + lr * Cn + rs0f;
  const u16* rb0k1 = sb[0] + lr * Cn + rs1;
  const u16* rb1k0 = sb[1] + lr * Cn + rs0f;
  const u16* rb1k1 = sb[1] + lr * Cn + rs1;
  (void)rs0;

  const f32x4 z4 = {0.f, 0.f, 0.f, 0.f};  // persistent zero C-operand

  // B fragments: qn rows as MFMA B (cols = p). Wave owns p in
  // [wave*112, wave*112+112): 7 pf x 16 p — exactly 448 total, no waste.
  short8 bq[NPF][2];
  const int p_lane = wave * (NPF * 16) + lr;  // + pf*16
#pragma unroll
  for (int pf = 0; pf < NPF; ++pf) {
    const u16* bp = Qb + (size_t)(p_lane + pf * 16) * Cn + lg * 8;
    bq[pf][0] = *(const short8*)(bp);
    bq[pf][1] = *(const short8*)(bp + 32);
  }

  // running top-3 per pf (this lane's p-col); sorted t0 >= t1 >= t2
  float t0[NPF], t1[NPF], t2[NPF];
#pragma unroll
  for (int e = 0; e < NPF; ++e) { t0[e] = NEG; t1[e] = NEG; t2[e] = NEG; }

  STAGE(0, 0);
  __syncthreads();  // vmcnt(0) drain + barrier

  // 34 full tiles, unrolled x2 so buffer selection is static
  for (int t = 0; t < NTILE - 1; t += 2) {
    STAGE(1, t + 1);
    COMPUTE_TILE(rb0k0, rb0k1, 0, 0);
    __syncthreads();
    STAGE(0, t + 2);
    COMPUTE_TILE(rb1k0, rb1k1, 0, 0);
    __syncthreads();
  }
  // tail tile 34 (buf 0): mask pad m rows (m >= 2205 -> NEG)
  COMPUTE_TILE(rb0k0, rb0k1, 1, (NTILE - 1) * MT);

  // finalize: merge top-3 across the 4 lg lanes sharing each p-col
  float total = 0.f;
#pragma unroll
  for (int pf = 0; pf < NPF; ++pf) {
    float a0 = t0[pf], a1 = t1[pf], a2 = t2[pf];
#pragma unroll
    for (int sh = 16; sh <= 32; sh <<= 1) {
      float b0 = __shfl_xor(a0, sh, 64);
      float b1 = __shfl_xor(a1, sh, 64);
      float b2 = __shfl_xor(a2, sh, 64);
      float n2 = MED3(a1, a2, b0);
      float n1 = MED3(a0, a1, b0);
      float n0 = fmaxf(a0, b0);
      n2 = MED3(n1, n2, b1);  // b1 <= b0 <= n0: max unneeded
      n1 = MED3(n0, n1, b1);
      n2 = MED3(n1, n2, b2);  // b2 can only land in slot 2
      a0 = n0; a1 = n1; a2 = n2;
    }
    const int p = p_lane + pf * 16;
    if (lg == 0 && p < Pn) total += a0 + a1 + a2;
  }

  // wave sum (non-lg0 lanes carry 0), then across 4 waves
#pragma unroll
  for (int sh = 1; sh <= 8; sh <<= 1) total += __shfl_xor(total, sh, 64);
  total += __shfl_xor(total, 16, 64);
  total += __shfl_xor(total, 32, 64);
  if (lane == 0) wsum[wave] = total;
  __syncthreads();
  if (tid == 0)
    out[(size_t)b * NWAY + j] = wsum[0] + wsum[1] + wsum[2] + wsum[3];
}

extern "C" void kernel_launch(void* const* d_in, const int* in_sizes, int n_in,
                              void* d_out, int out_size, void* d_ws,
                              size_t ws_size, hipStream_t stream) {
  (void)in_sizes; (void)n_in; (void)out_size; (void)ws_size;
  const float* q = (const float*)d_in[0];
  const float* S = (const float*)d_in[1];
  // d_in[2] = av_num == 1 per setup_inputs: geometric-mean branch not taken.
  float* out = (float*)d_out;

  u16* qn = (u16*)d_ws;                               // 128*448*64*2 = 7.34 MB
  u16* sn = qn + (size_t)Bn * PPAD * Cn;              // 50*2240*64*2 = 14.3 MB

  qnorm_kernel<<<(Bn * PPAD) / 256, 256, 0, stream>>>(q, qn);
  snorm_kernel<<<(NWAY * MPAD + 255) / 256, 256, 0, stream>>>(S, sn);
  knn_topk_kernel<<<Bn * NWAY, 256, 0, stream>>>(qn, sn, out);
}